// Round 5
// baseline (6581.911 us; speedup 1.0000x reference)
//
#include <hip/hip_runtime.h>
#include <hip/hip_bf16.h>
#include <stdint.h>

#define HW 192
#define PLANE (HW * HW)
#define OT 32  // output channels per block (2 n-frags of 16)

typedef __attribute__((ext_vector_type(8))) short frag8;
typedef __attribute__((ext_vector_type(4))) float f32x4;

// split v into hi/lo bf16, packed (hi<<16)|lo
__device__ inline uint32_t pack_split(float v) {
    __hip_bfloat16 h = __float2bfloat16(v);
    float hf = __bfloat162float(h);
    __hip_bfloat16 l = __float2bfloat16(v - hf);
    uint32_t hu = (uint32_t)__builtin_bit_cast(unsigned short, h);
    uint32_t lu = (uint32_t)__builtin_bit_cast(unsigned short, l);
    return (hu << 16) | lu;
}

// W[O][C_IN][3][3] f32 -> dst[C_IN/8][12][OPAD][8] packed u32 (taps 9..11 and o>=C_OUT zero)
__global__ __launch_bounds__(256) void wtrans_kernel(
    const float* __restrict__ w, uint32_t* __restrict__ dst,
    int C_IN, int C_OUT, int OPAD, int total)
{
    for (int idx = blockIdx.x * 256 + threadIdx.x; idx < total; idx += gridDim.x * 256) {
        int ic = idx & 7;
        int r = idx >> 3;
        int o = r % OPAD; r /= OPAD;
        int t = r % 12;
        int c8 = r / 12;
        float v = 0.f;
        if (t < 9 && o < C_OUT)
            v = w[((size_t)o * C_IN + c8 * 8 + ic) * 9 + t];
        dst[idx] = pack_split(v);
    }
}

// src [NB*64][PLANE] f32 -> dst [NB][8][PLANE][8] packed u32 (64 ch per batch)
__global__ __launch_bounds__(256) void packfx_kernel(
    const float* __restrict__ src, uint32_t* __restrict__ dst, int n)
{
    for (int idx = blockIdx.x * 256 + threadIdx.x; idx < n; idx += gridDim.x * 256) {
        int c = idx / PLANE;
        int p = idx - c * PLANE;
        int b = c >> 6;        // batch
        int cc = c & 63;       // channel within batch
        dst[(((size_t)(b * 8 + (cc >> 3))) * PLANE + p) * 8 + (cc & 7)] = pack_split(src[idx]);
    }
}

// 3x3 SAME conv via split-bf16 MFMA implicit GEMM. blockIdx.z = batch image.
// inp: [NCHUNK][PLANE][8] packed u32 per batch; wt: [NCHUNK][12][OPAD][8] packed u32.
// Block: 256 thr (4 waves), 32x32 spatial tile, OT=32 output channels.
// K-chunks of 32 = 4 tap-slots x 8 ic; taps padded to 12 (slots 9..11 zero weights).
// Same contiguous-8 k-labeling for A and B fragments -> HW k-permutation cancels.
template<int NCHUNK, int OPAD, bool LAST>
__global__ __launch_bounds__(256, 3) void conv_mfma(
    const uint32_t* __restrict__ inp, const uint32_t* __restrict__ wt,
    const float* __restrict__ bias, int c_out,
    uint32_t* __restrict__ outp, float* __restrict__ outf,
    size_t in_bstride, size_t out_bstride)
{
    __shared__ unsigned short s_xh[1156 * 8];   // halo 34x34 pixels x 8 ic, hi bf16
    __shared__ unsigned short s_xl[1156 * 8];   // lo bf16
    __shared__ unsigned short s_wh[12 * OT * 8];
    __shared__ unsigned short s_wl[12 * OT * 8];

    const int tid = threadIdx.x;
    const int wv = tid >> 6;
    const int lane = tid & 63;
    const int lq = lane >> 4;   // k-quarter / D-row group
    const int lr = lane & 15;   // A row (pixel) / B col (o) / D col
    const int tx0 = (blockIdx.x % 6) * 32;
    const int ty0 = (blockIdx.x / 6) * 32;
    const int obase = blockIdx.y * OT;

    const uint32_t* inpz = inp + (size_t)blockIdx.z * in_bstride;

    // per-lane tap offset (ushort units) into halo array, per k-quad q
    int hof[3];
    #pragma unroll
    for (int q = 0; q < 3; ++q) {
        int t = q * 4 + lq;
        int te = t > 8 ? 8 : t;   // pad slots read tap8's (valid) address; B there is zero
        int dy = te >= 6 ? 2 : (te >= 3 ? 1 : 0);
        int dx = te - dy * 3;
        hof[q] = (dy * 34 + dx) * 8;
    }

    f32x4 acc[16][2];
    #pragma unroll
    for (int mf = 0; mf < 16; ++mf)
        #pragma unroll
        for (int nf = 0; nf < 2; ++nf) {
            int o = obase + nf * 16 + lr;
            float bv = (o < c_out) ? bias[o] : 0.f;
            acc[mf][nf] = (f32x4){bv, bv, bv, bv};
        }

    for (int c8 = 0; c8 < NCHUNK; ++c8) {
        __syncthreads();
        // ---- stage input halo (zero OOB), unpack hi/lo ----
        const uint32_t* ibase = inpz + (size_t)c8 * PLANE * 8;
        for (int hp = tid; hp < 1156; hp += 256) {
            int r = hp / 34, c = hp - r * 34;
            int gy = ty0 + r - 1, gx = tx0 + c - 1;
            uint4 v0 = make_uint4(0, 0, 0, 0), v1 = make_uint4(0, 0, 0, 0);
            if (gy >= 0 && gy < HW && gx >= 0 && gx < HW) {
                const uint4* p = (const uint4*)&ibase[(size_t)(gy * HW + gx) * 8];
                v0 = p[0]; v1 = p[1];
            }
            uint32_t h0 = (v0.x >> 16) | (v0.y & 0xFFFF0000u);
            uint32_t h1 = (v0.z >> 16) | (v0.w & 0xFFFF0000u);
            uint32_t h2 = (v1.x >> 16) | (v1.y & 0xFFFF0000u);
            uint32_t h3 = (v1.z >> 16) | (v1.w & 0xFFFF0000u);
            uint32_t l0 = (v0.x & 0xFFFFu) | (v0.y << 16);
            uint32_t l1 = (v0.z & 0xFFFFu) | (v0.w << 16);
            uint32_t l2 = (v1.x & 0xFFFFu) | (v1.y << 16);
            uint32_t l3 = (v1.z & 0xFFFFu) | (v1.w << 16);
            ((uint4*)s_xh)[hp] = make_uint4(h0, h1, h2, h3);
            ((uint4*)s_xl)[hp] = make_uint4(l0, l1, l2, l3);
        }
        // ---- stage weights [12][OT][8] hi/lo ----
        const uint32_t* wbase = wt + (size_t)c8 * 12 * OPAD * 8;
        for (int i2 = tid; i2 < 12 * OT * 8 / 2; i2 += 256) {
            int flat = i2 * 2;
            int ic = flat & 7;
            int rest = flat >> 3;
            int o = rest & (OT - 1);
            int t = rest >> 5;
            const uint32_t* ws = &wbase[(size_t)(t * OPAD + obase + o) * 8 + ic];
            uint32_t w0 = ws[0], w1 = ws[1];
            ((uint32_t*)s_wh)[i2] = (w0 >> 16) | (w1 & 0xFFFF0000u);
            ((uint32_t*)s_wl)[i2] = (w0 & 0xFFFFu) | (w1 << 16);
        }
        __syncthreads();

        // ---- B fragments (shared across all m) ----
        frag8 bh[3][2], bl[3][2];
        #pragma unroll
        for (int q = 0; q < 3; ++q) {
            int t = q * 4 + lq;
            #pragma unroll
            for (int nf = 0; nf < 2; ++nf) {
                int a = (t * OT + nf * 16 + lr) * 8;
                bh[q][nf] = *(const frag8*)&s_wh[a];
                bl[q][nf] = *(const frag8*)&s_wl[a];
            }
        }
        // ---- MFMA over 16 m-frags x 2 n-frags x 3 k-quads x 3 passes ----
        #pragma unroll
        for (int mf = 0; mf < 16; ++mf) {
            int abase = ((wv * 8 + (mf >> 1)) * 34 + (mf & 1) * 16 + lr) * 8;
            frag8 ah[3], al[3];
            #pragma unroll
            for (int q = 0; q < 3; ++q) {
                ah[q] = *(const frag8*)&s_xh[abase + hof[q]];
                al[q] = *(const frag8*)&s_xl[abase + hof[q]];
            }
            #pragma unroll
            for (int nf = 0; nf < 2; ++nf)
                #pragma unroll
                for (int q = 0; q < 3; ++q) {
                    acc[mf][nf] = __builtin_amdgcn_mfma_f32_16x16x32_bf16(ah[q], bh[q][nf], acc[mf][nf], 0, 0, 0);
                    acc[mf][nf] = __builtin_amdgcn_mfma_f32_16x16x32_bf16(ah[q], bl[q][nf], acc[mf][nf], 0, 0, 0);
                    acc[mf][nf] = __builtin_amdgcn_mfma_f32_16x16x32_bf16(al[q], bh[q][nf], acc[mf][nf], 0, 0, 0);
                }
        }
    }

    // ---- epilogue: D row=(lq*4+j) -> pixel offset, col=lr -> o ----
    uint32_t* outpz = outp + (size_t)blockIdx.z * out_bstride;
    float*    outfz = outf + (size_t)blockIdx.z * out_bstride;
    #pragma unroll
    for (int mf = 0; mf < 16; ++mf) {
        int gy = ty0 + wv * 8 + (mf >> 1);
        int px = tx0 + (mf & 1) * 16 + lq * 4;
        #pragma unroll
        for (int nf = 0; nf < 2; ++nf) {
            int o = obase + nf * 16 + lr;
            if (LAST) {
                if (o < c_out) {
                    float4 v = make_float4(acc[mf][nf][0], acc[mf][nf][1],
                                           acc[mf][nf][2], acc[mf][nf][3]);
                    *(float4*)&outfz[(size_t)o * PLANE + gy * HW + px] = v;
                }
            } else {
                size_t base = ((size_t)(o >> 3) * PLANE + (size_t)gy * HW + px) * 8 + (o & 7);
                #pragma unroll
                for (int j = 0; j < 4; ++j)
                    outpz[base + (size_t)j * 8] = pack_split(acc[mf][nf][j]);
            }
        }
    }
}

// out[b,c,y,x] = sum_p ks_b[p*3+c, y, x] * xpad[b, c, y+p/5-2, x+p%5-2]
__global__ __launch_bounds__(256) void apply_kernel(
    const float* __restrict__ x, const float* __restrict__ ks,
    float* __restrict__ out, int total, size_t ks_bstride)
{
    int tid = blockIdx.x * 256 + threadIdx.x;
    if (tid >= total) return;
    int b = tid / PLANE;
    int pix = tid - b * PLANE;
    int y = pix / HW;
    int xc = pix - y * HW;

    const float* xb  = x  + (size_t)b * 3 * PLANE;
    const float* ksb = ks + (size_t)b * ks_bstride;
    float* ob        = out + (size_t)b * 3 * PLANE;

    float acc[3] = {0.f, 0.f, 0.f};
    #pragma unroll
    for (int p = 0; p < 25; ++p) {
        const int di = p / 5, dj = p % 5;
        int yy = y + di - 2, xx = xc + dj - 2;
        bool inb = (yy >= 0 && yy < HW && xx >= 0 && xx < HW);
        #pragma unroll
        for (int c = 0; c < 3; ++c) {
            float kv = ksb[((size_t)(p * 3 + c) * HW + y) * HW + xc];
            float xv = inb ? xb[((size_t)c * HW + yy) * HW + xx] : 0.f;
            acc[c] = fmaf(kv, xv, acc[c]);
        }
    }
    #pragma unroll
    for (int c = 0; c < 3; ++c)
        ob[((size_t)c * HW + y) * HW + xc] = acc[c];
}

extern "C" void kernel_launch(void* const* d_in, const int* in_sizes, int n_in,
                              void* d_out, int out_size, void* d_ws, size_t ws_size,
                              hipStream_t stream) {
    const float* feature_x = (const float*)d_in[0];
    const float* x  = (const float*)d_in[1];
    const float* W1 = (const float*)d_in[2];
    const float* b1 = (const float*)d_in[3];
    const float* W2 = (const float*)d_in[4];
    const float* b2 = (const float*)d_in[5];
    const float* W3 = (const float*)d_in[6];
    const float* b3 = (const float*)d_in[7];
    float* out = (float*)d_out;

    const size_t CH_STR = (size_t)32 * PLANE * 8;   // 9,437,184 u32 per batch (32-chunk tensor)
    const size_t FX_STR = (size_t)8 * PLANE * 8;    // 2,359,296 u32 per batch
    const size_t KS_STR = (size_t)75 * PLANE;       // f32 per batch

    dim3 blk(256);
    // Full-batch path needs: y1p(4) + y2p(4) + fxp(4) + weights = 86,212,608 u32 = 345 MB.
    const size_t FULL_U32 = CH_STR * 8 + FX_STR * 4 + 1277952;
    bool full = ws_size >= FULL_U32 * 4;

    if (full) {
        uint32_t* y1p = (uint32_t*)d_ws;            // [4][32][PLANE][8]
        uint32_t* y2p = y1p + CH_STR * 4;           // [4][32][PLANE][8]
        uint32_t* fxp = y2p + CH_STR * 4;           // [4][8][PLANE][8]
        uint32_t* wt1 = fxp + FX_STR * 4;
        uint32_t* wt2 = wt1 + 196608;
        uint32_t* wt3 = wt2 + 786432;
        float* ks = (float*)y1p;                    // alias y1p (free after conv2 of ALL batches)

        wtrans_kernel<<<256, blk, 0, stream>>>(W1, wt1, 64, 256, 256, 196608);
        wtrans_kernel<<<256, blk, 0, stream>>>(W2, wt2, 256, 256, 256, 786432);
        wtrans_kernel<<<256, blk, 0, stream>>>(W3, wt3, 256, 75, 96, 294912);
        packfx_kernel<<<1024, blk, 0, stream>>>(feature_x, fxp, 4 * 64 * PLANE);

        dim3 g12(36, 8, 4), g3(36, 3, 4), ga((4 * PLANE + 255) / 256);
        conv_mfma< 8, 256, false><<<g12, blk, 0, stream>>>(fxp, wt1, b1, 256, y1p, nullptr, FX_STR, CH_STR);
        conv_mfma<32, 256, false><<<g12, blk, 0, stream>>>(y1p, wt2, b2, 256, y2p, nullptr, CH_STR, CH_STR);
        conv_mfma<32,  96, true ><<<g3,  blk, 0, stream>>>(y2p, wt3, b3,  75, nullptr, ks, CH_STR, KS_STR);
        apply_kernel<<<ga, blk, 0, stream>>>(x, ks, out, 4 * PLANE, KS_STR);
    } else {
        // per-batch fallback (round-4 layout, ~92 MB)
        uint32_t* y1p = (uint32_t*)d_ws;            // [32][PLANE][8]
        uint32_t* y2p = y1p + CH_STR;               // [32][PLANE][8]
        uint32_t* regC = y2p + CH_STR;              // max(fxp, ks)
        uint32_t* fxp = regC;
        float*    ks  = (float*)regC;
        uint32_t* wt1 = regC + 2764800;
        uint32_t* wt2 = wt1 + 196608;
        uint32_t* wt3 = wt2 + 786432;

        wtrans_kernel<<<256, blk, 0, stream>>>(W1, wt1, 64, 256, 256, 196608);
        wtrans_kernel<<<256, blk, 0, stream>>>(W2, wt2, 256, 256, 256, 786432);
        wtrans_kernel<<<256, blk, 0, stream>>>(W3, wt3, 256, 75, 96, 294912);

        dim3 g12(36, 8, 1), g3(36, 3, 1), ga((PLANE + 255) / 256);
        for (int b = 0; b < 4; ++b) {
            const float* fx_b = feature_x + (size_t)b * 64 * PLANE;
            const float* x_b  = x + (size_t)b * 3 * PLANE;
            float* out_b      = out + (size_t)b * 3 * PLANE;
            packfx_kernel<<<256, blk, 0, stream>>>(fx_b, fxp, 64 * PLANE);
            conv_mfma< 8, 256, false><<<g12, blk, 0, stream>>>(fxp, wt1, b1, 256, y1p, nullptr, 0, 0);
            conv_mfma<32, 256, false><<<g12, blk, 0, stream>>>(y1p, wt2, b2, 256, y2p, nullptr, 0, 0);
            conv_mfma<32,  96, true ><<<g3,  blk, 0, stream>>>(y2p, wt3, b3,  75, nullptr, ks, 0, 0);
            apply_kernel<<<ga, blk, 0, stream>>>(x_b, ks, out_b, PLANE, 0);
        }
    }
}

// Round 6
// 2293.716 us; speedup vs baseline: 2.8695x; 2.8695x over previous
//
#include <hip/hip_runtime.h>
#include <hip/hip_bf16.h>
#include <stdint.h>

#define HW 192
#define PLANE (HW * HW)
#define OT 32      // output channels per block (2 n-frags of 16)
#define TILE_W 32
#define TILE_H 16
#define HC 34      // halo cols
#define HR 18      // halo rows
#define HPX (HR * HC)  // 612 halo pixels

typedef __attribute__((ext_vector_type(8))) short frag8;
typedef __attribute__((ext_vector_type(4))) float f32x4;

// split v into hi/lo bf16, packed (hi<<16)|lo
__device__ inline uint32_t pack_split(float v) {
    __hip_bfloat16 h = __float2bfloat16(v);
    float hf = __bfloat162float(h);
    __hip_bfloat16 l = __float2bfloat16(v - hf);
    uint32_t hu = (uint32_t)__builtin_bit_cast(unsigned short, h);
    uint32_t lu = (uint32_t)__builtin_bit_cast(unsigned short, l);
    return (hu << 16) | lu;
}

// W[O][C_IN][3][3] f32 -> dst[C_IN/8][12][OPAD][8] packed u32 (taps 9..11 and o>=C_OUT zero)
__global__ __launch_bounds__(256) void wtrans_kernel(
    const float* __restrict__ w, uint32_t* __restrict__ dst,
    int C_IN, int C_OUT, int OPAD, int total)
{
    for (int idx = blockIdx.x * 256 + threadIdx.x; idx < total; idx += gridDim.x * 256) {
        int ic = idx & 7;
        int r = idx >> 3;
        int o = r % OPAD; r /= OPAD;
        int t = r % 12;
        int c8 = r / 12;
        float v = 0.f;
        if (t < 9 && o < C_OUT)
            v = w[((size_t)o * C_IN + c8 * 8 + ic) * 9 + t];
        dst[idx] = pack_split(v);
    }
}

// fx [64][H][W] f32 -> dst [8][H][W][8] packed u32 (one batch)
__global__ __launch_bounds__(256) void packfx_kernel(
    const float* __restrict__ src, uint32_t* __restrict__ dst, int n)
{
    for (int idx = blockIdx.x * 256 + threadIdx.x; idx < n; idx += gridDim.x * 256) {
        int c = idx / PLANE;
        int p = idx - c * PLANE;
        dst[((size_t)(c >> 3) * PLANE + p) * 8 + (c & 7)] = pack_split(src[idx]);
    }
}

// 3x3 SAME conv via split-bf16 MFMA implicit GEMM. One batch image.
// inp: [NCHUNK][PLANE][8] packed u32; wt: [NCHUNK][12][OPAD][8] packed u32.
// Block: 256 thr (4 waves), 16x32 spatial tile, OT=32 output channels.
// K-chunks of 32 = 4 tap-slots x 8 ic; taps padded to 12 (slots 9..11 zero weights).
// Same contiguous-8 k-labeling for A and B fragments -> HW k-permutation cancels.
template<int NCHUNK, int OPAD, bool LAST>
__global__ __launch_bounds__(256, 2) void conv_mfma(
    const uint32_t* __restrict__ inp, const uint32_t* __restrict__ wt,
    const float* __restrict__ bias, int c_out,
    uint32_t* __restrict__ outp, float* __restrict__ outf)
{
    __shared__ unsigned short s_xh[HPX * 8];   // halo 18x34 pixels x 8 ic, hi bf16
    __shared__ unsigned short s_xl[HPX * 8];   // lo bf16
    __shared__ unsigned short s_wh[12 * OT * 8];
    __shared__ unsigned short s_wl[12 * OT * 8];

    const int tid = threadIdx.x;
    const int wv = tid >> 6;
    const int lane = tid & 63;
    const int lq = lane >> 4;   // k-quarter / D-row group
    const int lr = lane & 15;   // A row (pixel) / B col (o) / D col
    const int tx0 = (blockIdx.x % 6) * TILE_W;
    const int ty0 = (blockIdx.x / 6) * TILE_H;
    const int obase = blockIdx.y * OT;

    // per-lane tap offset (ushort units) into halo array, per k-quad q
    int hof[3];
    #pragma unroll
    for (int q = 0; q < 3; ++q) {
        int t = q * 4 + lq;
        int te = t > 8 ? 8 : t;   // pad slots read tap8's (valid) address; B there is zero
        int dy = te >= 6 ? 2 : (te >= 3 ? 1 : 0);
        int dx = te - dy * 3;
        hof[q] = (dy * HC + dx) * 8;
    }

    f32x4 acc[8][2];
    #pragma unroll
    for (int mf = 0; mf < 8; ++mf)
        #pragma unroll
        for (int nf = 0; nf < 2; ++nf) {
            int o = obase + nf * 16 + lr;
            float bv = (o < c_out) ? bias[o] : 0.f;
            acc[mf][nf] = (f32x4){bv, bv, bv, bv};
        }

    for (int c8 = 0; c8 < NCHUNK; ++c8) {
        __syncthreads();
        // ---- stage input halo (zero OOB), unpack hi/lo ----
        const uint32_t* ibase = inp + (size_t)c8 * PLANE * 8;
        for (int hp = tid; hp < HPX; hp += 256) {
            int r = hp / HC, c = hp - r * HC;
            int gy = ty0 + r - 1, gx = tx0 + c - 1;
            uint4 v0 = make_uint4(0, 0, 0, 0), v1 = make_uint4(0, 0, 0, 0);
            if (gy >= 0 && gy < HW && gx >= 0 && gx < HW) {
                const uint4* p = (const uint4*)&ibase[(size_t)(gy * HW + gx) * 8];
                v0 = p[0]; v1 = p[1];
            }
            uint32_t h0 = (v0.x >> 16) | (v0.y & 0xFFFF0000u);
            uint32_t h1 = (v0.z >> 16) | (v0.w & 0xFFFF0000u);
            uint32_t h2 = (v1.x >> 16) | (v1.y & 0xFFFF0000u);
            uint32_t h3 = (v1.z >> 16) | (v1.w & 0xFFFF0000u);
            uint32_t l0 = (v0.x & 0xFFFFu) | (v0.y << 16);
            uint32_t l1 = (v0.z & 0xFFFFu) | (v0.w << 16);
            uint32_t l2 = (v1.x & 0xFFFFu) | (v1.y << 16);
            uint32_t l3 = (v1.z & 0xFFFFu) | (v1.w << 16);
            ((uint4*)s_xh)[hp] = make_uint4(h0, h1, h2, h3);
            ((uint4*)s_xl)[hp] = make_uint4(l0, l1, l2, l3);
        }
        // ---- stage weights [12][OT][8] hi/lo ----
        const uint32_t* wbase = wt + (size_t)c8 * 12 * OPAD * 8;
        for (int i2 = tid; i2 < 12 * OT * 8 / 2; i2 += 256) {
            int flat = i2 * 2;
            int ic = flat & 7;
            int rest = flat >> 3;
            int o = rest & (OT - 1);
            int t = rest >> 5;
            const uint32_t* ws = &wbase[(size_t)(t * OPAD + obase + o) * 8 + ic];
            uint32_t w0 = ws[0], w1 = ws[1];
            ((uint32_t*)s_wh)[i2] = (w0 >> 16) | (w1 & 0xFFFF0000u);
            ((uint32_t*)s_wl)[i2] = (w0 & 0xFFFFu) | (w1 << 16);
        }
        __syncthreads();

        // ---- B fragments (shared across all m) ----
        frag8 bh[3][2], bl[3][2];
        #pragma unroll
        for (int q = 0; q < 3; ++q) {
            int t = q * 4 + lq;
            #pragma unroll
            for (int nf = 0; nf < 2; ++nf) {
                int a = (t * OT + nf * 16 + lr) * 8;
                bh[q][nf] = *(const frag8*)&s_wh[a];
                bl[q][nf] = *(const frag8*)&s_wl[a];
            }
        }
        // ---- MFMA over 8 m-frags x 2 n-frags x 3 k-quads x 3 passes ----
        #pragma unroll
        for (int mf = 0; mf < 8; ++mf) {
            int abase = ((wv * 4 + (mf >> 1)) * HC + (mf & 1) * 16 + lr) * 8;
            frag8 ah[3], al[3];
            #pragma unroll
            for (int q = 0; q < 3; ++q) {
                ah[q] = *(const frag8*)&s_xh[abase + hof[q]];
                al[q] = *(const frag8*)&s_xl[abase + hof[q]];
            }
            #pragma unroll
            for (int nf = 0; nf < 2; ++nf)
                #pragma unroll
                for (int q = 0; q < 3; ++q) {
                    acc[mf][nf] = __builtin_amdgcn_mfma_f32_16x16x32_bf16(ah[q], bh[q][nf], acc[mf][nf], 0, 0, 0);
                    acc[mf][nf] = __builtin_amdgcn_mfma_f32_16x16x32_bf16(ah[q], bl[q][nf], acc[mf][nf], 0, 0, 0);
                    acc[mf][nf] = __builtin_amdgcn_mfma_f32_16x16x32_bf16(al[q], bh[q][nf], acc[mf][nf], 0, 0, 0);
                }
        }
    }

    // ---- epilogue: D row=(lq*4+j) -> pixel offset, col=lr -> o ----
    #pragma unroll
    for (int mf = 0; mf < 8; ++mf) {
        int gy = ty0 + wv * 4 + (mf >> 1);
        int px = tx0 + (mf & 1) * 16 + lq * 4;
        #pragma unroll
        for (int nf = 0; nf < 2; ++nf) {
            int o = obase + nf * 16 + lr;
            if (LAST) {
                if (o < c_out) {
                    float4 v = make_float4(acc[mf][nf][0], acc[mf][nf][1],
                                           acc[mf][nf][2], acc[mf][nf][3]);
                    *(float4*)&outf[(size_t)o * PLANE + gy * HW + px] = v;
                }
            } else {
                size_t base = ((size_t)(o >> 3) * PLANE + (size_t)gy * HW + px) * 8 + (o & 7);
                #pragma unroll
                for (int j = 0; j < 4; ++j)
                    outp[base + (size_t)j * 8] = pack_split(acc[mf][nf][j]);
            }
        }
    }
}

// One batch image. out[c,y,x] = sum_p ks[p*3+c, y, x] * xpad[c, y+p/5-2, x+p%5-2]
__global__ __launch_bounds__(256) void apply_kernel(
    const float* __restrict__ x, const float* __restrict__ ks,
    float* __restrict__ out)
{
    int tid = blockIdx.x * 256 + threadIdx.x;
    if (tid >= PLANE) return;
    int y = tid / HW;
    int xc = tid - y * HW;

    float acc[3] = {0.f, 0.f, 0.f};
    #pragma unroll
    for (int p = 0; p < 25; ++p) {
        const int di = p / 5, dj = p % 5;
        int yy = y + di - 2, xx = xc + dj - 2;
        bool inb = (yy >= 0 && yy < HW && xx >= 0 && xx < HW);
        #pragma unroll
        for (int c = 0; c < 3; ++c) {
            float kv = ks[((size_t)(p * 3 + c) * HW + y) * HW + xc];
            float xv = inb ? x[((size_t)c * HW + yy) * HW + xx] : 0.f;
            acc[c] = fmaf(kv, xv, acc[c]);
        }
    }
    #pragma unroll
    for (int c = 0; c < 3; ++c)
        out[((size_t)c * HW + y) * HW + xc] = acc[c];
}

extern "C" void kernel_launch(void* const* d_in, const int* in_sizes, int n_in,
                              void* d_out, int out_size, void* d_ws, size_t ws_size,
                              hipStream_t stream) {
    const float* feature_x = (const float*)d_in[0];
    const float* x  = (const float*)d_in[1];
    const float* W1 = (const float*)d_in[2];
    const float* b1 = (const float*)d_in[3];
    const float* W2 = (const float*)d_in[4];
    const float* b2 = (const float*)d_in[5];
    const float* W3 = (const float*)d_in[6];
    const float* b3 = (const float*)d_in[7];
    float* out = (float*)d_out;

    // workspace layout (u32 units), ~92 MB total (round-4 proven)
    uint32_t* y1p = (uint32_t*)d_ws;                       // [32][PLANE][8]
    uint32_t* y2p = y1p + (size_t)32 * PLANE * 8;          // [32][PLANE][8]
    uint32_t* regC = y2p + (size_t)32 * PLANE * 8;         // max(fxp 2.36M, ks 2.76M)
    uint32_t* fxp = regC;                                  // [8][PLANE][8]
    float*    ks  = (float*)regC;                          // [75][H][W]
    uint32_t* wt1 = regC + 2764800;
    uint32_t* wt2 = wt1 + 196608;
    uint32_t* wt3 = wt2 + 786432;

    dim3 blk(256);
    // weight transforms (shared across batches)
    wtrans_kernel<<<256, blk, 0, stream>>>(W1, wt1, 64, 256, 256, 196608);
    wtrans_kernel<<<256, blk, 0, stream>>>(W2, wt2, 256, 256, 256, 786432);
    wtrans_kernel<<<256, blk, 0, stream>>>(W3, wt3, 256, 75, 96, 294912);

    // 16x32 tiles: 6 x-tiles, 12 y-tiles = 72 spatial blocks
    dim3 g12(72, 8), g3(72, 3), ga((PLANE + 255) / 256);
    for (int b = 0; b < 4; ++b) {
        const float* fx_b = feature_x + (size_t)b * 64 * PLANE;
        const float* x_b  = x + (size_t)b * 3 * PLANE;
        float* out_b      = out + (size_t)b * 3 * PLANE;
        packfx_kernel<<<256, blk, 0, stream>>>(fx_b, fxp, 64 * PLANE);
        conv_mfma< 8, 256, false><<<g12, blk, 0, stream>>>(fxp, wt1, b1, 256, y1p, nullptr);
        conv_mfma<32, 256, false><<<g12, blk, 0, stream>>>(y1p, wt2, b2, 256, y2p, nullptr);
        conv_mfma<32,  96, true ><<<g3,  blk, 0, stream>>>(y2p, wt3, b3,  75, nullptr, ks);
        apply_kernel<<<ga, blk, 0, stream>>>(x_b, ks, out_b);
    }
}